// Round 5
// baseline (205.747 us; speedup 1.0000x reference)
//
#include <hip/hip_runtime.h>
#include <math.h>

// Problem constants
#define BSZ    2
#define LSEQ   2048
#define DI     2048
#define DSTATE 8
#define DTRANK 256
#define KXP    (DTRANK + 2 * DSTATE)   // 272
#define NPAD   288                     // KXP padded to 18*16 for MFMA tiles
#define NC     64                      // scan chunks
#define CL     (LSEQ / NC)             // 32
#define KSPLIT 8                       // gemm1 K-splits (bf16 partials)

#define NWXP (288u * 2048u)            // 589824 (padded)
#define NWX  (272u * 2048u)            // 557056 (real)
#define NWDT (2048u * 256u)            // 524288

typedef __attribute__((ext_vector_type(8))) short bf16x8;
typedef __attribute__((ext_vector_type(4))) float f32x4;

static __device__ __forceinline__ unsigned short f2bf(float f) {
    unsigned u = __float_as_uint(f);
    u += 0x7fff + ((u >> 16) & 1);   // round-to-nearest-even
    return (unsigned short)(u >> 16);
}
static __device__ __forceinline__ float bf2f(unsigned short s) {
    return __uint_as_float((unsigned)s << 16);
}

static __device__ __forceinline__ float softplus_fast(float z) {
    const float e = __expf(-fabsf(z));
    return fmaxf(z, 0.0f) + __logf(1.0f + e);
}

// ---------------------------------------------------------------------------
// Convert weight matrices to bf16: W_xproj (272x2048 -> padded 288x2048) and
// W_dt (2048x256). 4 elems/thread. (x stays fp32; gemm1 converts in-register.)
// ---------------------------------------------------------------------------
__global__ __launch_bounds__(256) void convert_w(const float* __restrict__ Wx,
                                                 const float* __restrict__ Wdt,
                                                 unsigned short* __restrict__ Wxb,
                                                 unsigned short* __restrict__ Wdtb) {
    const unsigned tid = blockIdx.x * 256 + threadIdx.x;
    const unsigned i4 = tid * 4;
    float4 v;
    unsigned short* dst;
    unsigned j;
    if (i4 < NWXP) {
        j = i4;
        v = (j < NWX) ? *(const float4*)&Wx[j] : make_float4(0.f, 0.f, 0.f, 0.f);
        dst = Wxb;
    } else {
        j = i4 - NWXP;
        if (j >= NWDT) return;
        v = *(const float4*)&Wdt[j];
        dst = Wdtb;
    }
    ushort4 o;
    o.x = f2bf(v.x); o.y = f2bf(v.y); o.z = f2bf(v.z); o.w = f2bf(v.w);
    *(ushort4*)&dst[j] = o;
}

// ---------------------------------------------------------------------------
// GEMM1 (MFMA, split-K, bf16 partials):
//   partb[ks][4096][288] = bf16( x[., ks-chunk] @ Wxb^T )
// grid (128 Mtiles of BM=32, 8 Ksplits) = 1024 blocks, 4/CU for latency hiding.
// 4 waves: wave = (rowhalf, nhalf); each wave 16 rows x 144 cols (9 frags).
// ---------------------------------------------------------------------------
__global__ __launch_bounds__(256) void gemm1_mfma(const float* __restrict__ x,
                                                  const unsigned short* __restrict__ Wxb,
                                                  unsigned short* __restrict__ partb) {
    const int mt   = blockIdx.x;   // 0..127
    const int ks   = blockIdx.y;   // 0..7
    const int wave = threadIdx.x >> 6;
    const int lane = threadIdx.x & 63;
    const int quad = lane >> 4;
    const int r    = lane & 15;
    const int kq   = quad * 8;
    const int rh   = wave >> 1;          // row half
    const int nh   = wave & 1;           // N half
    const int mbase  = mt * 32 + rh * 16;
    const int nfrag0 = nh * 9;
    const size_t arow = (size_t)(mbase + r) * DI;   // fp32 row of x
    const size_t brow = (size_t)r * DI;

    f32x4 acc[9];
#pragma unroll
    for (int n = 0; n < 9; n++) acc[n] = (f32x4)(0.0f);

    const int kbeg = ks * (DI / KSPLIT);
#pragma unroll 2
    for (int k0 = kbeg; k0 < kbeg + DI / KSPLIT; k0 += 32) {
        const float4 u0 = *(const float4*)&x[arow + k0 + kq];
        const float4 u1 = *(const float4*)&x[arow + k0 + kq + 4];
        bf16x8 a;
        a[0] = (short)f2bf(u0.x); a[1] = (short)f2bf(u0.y);
        a[2] = (short)f2bf(u0.z); a[3] = (short)f2bf(u0.w);
        a[4] = (short)f2bf(u1.x); a[5] = (short)f2bf(u1.y);
        a[6] = (short)f2bf(u1.z); a[7] = (short)f2bf(u1.w);
#pragma unroll
        for (int nf = 0; nf < 9; nf++) {
            const bf16x8 b = *(const bf16x8*)&Wxb[brow + (size_t)(nfrag0 + nf) * (16 * DI) + k0 + kq];
            acc[nf] = __builtin_amdgcn_mfma_f32_16x16x32_bf16(a, b, acc[nf], 0, 0, 0);
        }
    }

    unsigned short* p = partb + (size_t)ks * 4096 * NPAD;
    const int row0 = mbase + quad * 4;
#pragma unroll
    for (int nf = 0; nf < 9; nf++) {
        const int col = (nfrag0 + nf) * 16 + r;
#pragma unroll
        for (int i = 0; i < 4; i++)
            p[(size_t)(row0 + i) * NPAD + col] = f2bf(acc[nf][i]);
    }
}

// ---------------------------------------------------------------------------
// Reduce split-K bf16 partials -> xdbl fp32 [4096][272]; also emit dtr bf16
// [4096][256] for GEMM2. 4 cols/thread.
// ---------------------------------------------------------------------------
__global__ __launch_bounds__(256) void reduce1(const unsigned short* __restrict__ partb,
                                               float* __restrict__ xdbl,
                                               unsigned short* __restrict__ dtr) {
    const int tid = blockIdx.x * 256 + threadIdx.x;  // 4096*72
    const int row = tid / 72;
    const int c4  = (tid - row * 72) * 4;
    float4 s = make_float4(0.f, 0.f, 0.f, 0.f);
#pragma unroll
    for (int ks = 0; ks < KSPLIT; ks++) {
        const ushort4 v = *(const ushort4*)&partb[(size_t)ks * 4096 * NPAD + (size_t)row * NPAD + c4];
        s.x += bf2f(v.x); s.y += bf2f(v.y); s.z += bf2f(v.z); s.w += bf2f(v.w);
    }
    if (c4 < KXP) *(float4*)&xdbl[(size_t)row * KXP + c4] = s;
    if (c4 < DTRANK) {
        ushort4 o;
        o.x = f2bf(s.x); o.y = f2bf(s.y); o.z = f2bf(s.z); o.w = f2bf(s.w);
        *(ushort4*)&dtr[(size_t)row * DTRANK + c4] = o;
    }
}

// ---------------------------------------------------------------------------
// GEMM2 (MFMA, LDS-staged): delta[4096][2048] = softplus(dtr @ Wdtb^T + b_dt).
// K=256, BK=32. 128x128 block tile, 4 waves each 64x64 (4x4 frags).
// LDS row stride padded 32->40 shorts (80 B) to break bank conflicts.
// ---------------------------------------------------------------------------
#define G2RS 40
__global__ __launch_bounds__(256, 2) void gemm2_mfma(const unsigned short* __restrict__ dtr,
                                                     const unsigned short* __restrict__ Wdtb,
                                                     const float* __restrict__ bdt,
                                                     float* __restrict__ delta) {
    __shared__ __align__(16) unsigned short As[128 * G2RS];
    __shared__ __align__(16) unsigned short Bs[128 * G2RS];
    const int nt   = blockIdx.x;
    const int mt   = blockIdx.y;
    const int t    = threadIdx.x;
    const int wave = t >> 6;
    const int lane = t & 63;
    const int quad = lane >> 4;
    const int r    = lane & 15;
    const int m0 = mt * 128, n0 = nt * 128;
    const int mw = (wave >> 1) * 64, nw = (wave & 1) * 64;

    const int srow = t >> 1;             // 0..127
    const int sc   = (t & 1) * 16;       // 0 or 16 shorts

    f32x4 acc[4][4];
#pragma unroll
    for (int f = 0; f < 4; f++)
#pragma unroll
        for (int g = 0; g < 4; g++) acc[f][g] = (f32x4)(0.0f);

    for (int k0 = 0; k0 < DTRANK; k0 += 32) {
        const bf16x8 a0 = *(const bf16x8*)&dtr[(size_t)(m0 + srow) * DTRANK + k0 + sc];
        const bf16x8 a1 = *(const bf16x8*)&dtr[(size_t)(m0 + srow) * DTRANK + k0 + sc + 8];
        const bf16x8 b0 = *(const bf16x8*)&Wdtb[(size_t)(n0 + srow) * DTRANK + k0 + sc];
        const bf16x8 b1 = *(const bf16x8*)&Wdtb[(size_t)(n0 + srow) * DTRANK + k0 + sc + 8];
        __syncthreads();
        *(bf16x8*)&As[srow * G2RS + sc]     = a0;
        *(bf16x8*)&As[srow * G2RS + sc + 8] = a1;
        *(bf16x8*)&Bs[srow * G2RS + sc]     = b0;
        *(bf16x8*)&Bs[srow * G2RS + sc + 8] = b1;
        __syncthreads();

        bf16x8 a[4], b[4];
#pragma unroll
        for (int f = 0; f < 4; f++)
            a[f] = *(const bf16x8*)&As[(mw + f * 16 + r) * G2RS + quad * 8];
#pragma unroll
        for (int g = 0; g < 4; g++)
            b[g] = *(const bf16x8*)&Bs[(nw + g * 16 + r) * G2RS + quad * 8];
#pragma unroll
        for (int f = 0; f < 4; f++)
#pragma unroll
            for (int g = 0; g < 4; g++)
                acc[f][g] = __builtin_amdgcn_mfma_f32_16x16x32_bf16(a[f], b[g], acc[f][g], 0, 0, 0);
    }

#pragma unroll
    for (int f = 0; f < 4; f++) {
        const int row0 = m0 + mw + f * 16 + quad * 4;
#pragma unroll
        for (int g = 0; g < 4; g++) {
            const int col = n0 + nw + g * 16 + r;
            const float bv = bdt[col];
#pragma unroll
            for (int i = 0; i < 4; i++)
                delta[(size_t)(row0 + i) * DI + col] = softplus_fast(acc[f][g][i] + bv);
        }
    }
}

// ---------------------------------------------------------------------------
// Scan pass 1: per (b, chunk, d) chunk summary (P = prod dA, H = h_end), h=0.
// grid: BSZ*NC*8 = 1024 blocks. B rows staged in LDS (broadcast reads).
// ---------------------------------------------------------------------------
__global__ __launch_bounds__(256) void scan_pass1(const float* __restrict__ x,
                                                  const float* __restrict__ delta,
                                                  const float* __restrict__ xdbl,
                                                  const float* __restrict__ Alog,
                                                  float* __restrict__ Pb,
                                                  float* __restrict__ Hb) {
    __shared__ __align__(16) float Ls[CL * 8];
    const int bi   = blockIdx.x;
    const int b    = bi >> 9;
    const int c    = (bi >> 3) & 63;
    const int dblk = bi & 7;
    const int d    = dblk * 256 + threadIdx.x;
    const int l0   = c * CL;
    const size_t row0 = (size_t)b * LSEQ + l0;

    if (threadIdx.x < CL * 2) {
        const int l = threadIdx.x >> 1, part = (threadIdx.x & 1) * 4;
        const float4 v = *(const float4*)&xdbl[(row0 + l) * KXP + DTRANK + part];
        *(float4*)&Ls[l * 8 + part] = v;
    }

    float A[8], h[8], P[8];
#pragma unroll
    for (int n = 0; n < 8; n++) {
        A[n] = -__expf(Alog[d * 8 + n]);
        h[n] = 0.f;
        P[n] = 1.f;
    }
    __syncthreads();

#pragma unroll 4
    for (int l = 0; l < CL; l++) {
        const size_t row = row0 + l;
        const float dl = delta[row * DI + d];
        const float xv = x[row * DI + d];
        const float du = dl * xv;
#pragma unroll
        for (int n = 0; n < 8; n++) {
            const float dA = __expf(dl * A[n]);
            h[n] = dA * h[n] + du * Ls[l * 8 + n];
            P[n] *= dA;
        }
    }
    const size_t base = ((size_t)(b * NC + c) * DI + d) * 8;
    *(float4*)&Pb[base]     = make_float4(P[0], P[1], P[2], P[3]);
    *(float4*)&Pb[base + 4] = make_float4(P[4], P[5], P[6], P[7]);
    *(float4*)&Hb[base]     = make_float4(h[0], h[1], h[2], h[3]);
    *(float4*)&Hb[base + 4] = make_float4(h[4], h[5], h[6], h[7]);
}

// ---------------------------------------------------------------------------
// Scan pass 2: combine NC chunk summaries -> h0 entering each chunk.
// One thread per (b, d, n) scalar chain: 32768 threads, coalesced.
// ---------------------------------------------------------------------------
__global__ __launch_bounds__(256) void scan_pass2(const float* __restrict__ Pb,
                                                  const float* __restrict__ Hb,
                                                  float* __restrict__ h0) {
    const int t   = blockIdx.x * 256 + threadIdx.x;  // 0..32767
    const int b   = t >> 14;
    const int rem = t & 16383;                       // d*8+n
    float h = 0.f;
#pragma unroll 4
    for (int c = 0; c < NC; c++) {
        const size_t base = (size_t)(b * NC + c) * (DI * 8) + rem;
        h0[base] = h;
        h = Pb[base] * h + Hb[base];
    }
}

// ---------------------------------------------------------------------------
// Scan pass 3: re-scan each chunk from h0, produce y. B/C staged in LDS.
// ---------------------------------------------------------------------------
__global__ __launch_bounds__(256) void scan_pass3(const float* __restrict__ x,
                                                  const float* __restrict__ delta,
                                                  const float* __restrict__ xdbl,
                                                  const float* __restrict__ Alog,
                                                  const float* __restrict__ Dp,
                                                  const float* __restrict__ h0,
                                                  float* __restrict__ y) {
    __shared__ __align__(16) float Ls[CL * 16];
    const int bi   = blockIdx.x;
    const int b    = bi >> 9;
    const int c    = (bi >> 3) & 63;
    const int dblk = bi & 7;
    const int d    = dblk * 256 + threadIdx.x;
    const int l0   = c * CL;
    const size_t row0 = (size_t)b * LSEQ + l0;

    if (threadIdx.x < CL * 4) {
        const int l = threadIdx.x >> 2, part = (threadIdx.x & 3) * 4;
        const float4 v = *(const float4*)&xdbl[(row0 + l) * KXP + DTRANK + part];
        *(float4*)&Ls[l * 16 + part] = v;
    }

    float A[8], h[8];
    const size_t hbase = ((size_t)(b * NC + c) * DI + d) * 8;
    const float4 h0a = *(const float4*)&h0[hbase];
    const float4 h0b = *(const float4*)&h0[hbase + 4];
    h[0] = h0a.x; h[1] = h0a.y; h[2] = h0a.z; h[3] = h0a.w;
    h[4] = h0b.x; h[5] = h0b.y; h[6] = h0b.z; h[7] = h0b.w;
#pragma unroll
    for (int n = 0; n < 8; n++) A[n] = -__expf(Alog[d * 8 + n]);
    const float Dpar = Dp[d];
    __syncthreads();

#pragma unroll 4
    for (int l = 0; l < CL; l++) {
        const size_t row = row0 + l;
        const float dl = delta[row * DI + d];
        const float xv = x[row * DI + d];
        const float du = dl * xv;
        float yv = 0.f;
#pragma unroll
        for (int n = 0; n < 8; n++) {
            const float dA = __expf(dl * A[n]);
            h[n] = dA * h[n] + du * Ls[l * 16 + n];
            yv += h[n] * Ls[l * 16 + 8 + n];
        }
        yv += xv * Dpar;
        y[row * DI + d] = yv;
    }
}

// ---------------------------------------------------------------------------
extern "C" void kernel_launch(void* const* d_in, const int* in_sizes, int n_in,
                              void* d_out, int out_size, void* d_ws, size_t ws_size,
                              hipStream_t stream) {
    const float* x    = (const float*)d_in[0];
    const float* Wx   = (const float*)d_in[1];
    const float* Wdt  = (const float*)d_in[2];
    const float* bdt  = (const float*)d_in[3];
    const float* Alog = (const float*)d_in[4];
    const float* Dp   = (const float*)d_in[5];
    float* y = (float*)d_out;

    // Workspace (floats unless noted). delta aliases partb (dead after reduce1).
    //   partb : 8*4096*288 bf16 = 9,437,184 sh = 4,718,592 f  @ 0
    //   delta : 8,388,608 f                                   @ 0   (alias)
    //   xdbl  : 1,114,112 f  @ 8,388,608
    //   Pb/Hb/h0 : 3 x 2,097,152 f  (BSZ*NC*DI*8, NC=64)
    //   Wxb (589,824 sh) | Wdtb (524,288 sh) | dtr (1,048,576 sh)
    // total ~67.5 MB (same as round 4)
    float* ws    = (float*)d_ws;
    unsigned short* partb = (unsigned short*)ws;
    float* delta = ws;                       // alias (after reduce1)
    float* xdbl  = ws + 8388608;
    float* Pb    = xdbl + 1114112;
    float* Hb    = Pb + 2097152;
    float* h0    = Hb + 2097152;
    unsigned short* Wxb  = (unsigned short*)(h0 + 2097152);
    unsigned short* Wdtb = Wxb + (size_t)NWXP;
    unsigned short* dtr  = Wdtb + (size_t)NWDT;

    dim3 blk(256);
    hipLaunchKernelGGL(convert_w, dim3((NWXP + NWDT) / 4 / 256), blk, 0, stream,
                       Wx, Wdt, Wxb, Wdtb);
    hipLaunchKernelGGL(gemm1_mfma, dim3(128, KSPLIT), blk, 0, stream, x, Wxb, partb);
    hipLaunchKernelGGL(reduce1, dim3(4096 * 72 / 256), blk, 0, stream, partb, xdbl, dtr);
    hipLaunchKernelGGL(gemm2_mfma, dim3(16, 32), blk, 0, stream, dtr, Wdtb, bdt, delta);
    hipLaunchKernelGGL(scan_pass1, dim3(BSZ * NC * 8), blk, 0, stream, x, delta, xdbl, Alog, Pb, Hb);
    hipLaunchKernelGGL(scan_pass2, dim3(128), blk, 0, stream, Pb, Hb, h0);
    hipLaunchKernelGGL(scan_pass3, dim3(BSZ * NC * 8), blk, 0, stream, x, delta, xdbl, Alog, Dp, h0, y);
}

// Round 6
// 181.834 us; speedup vs baseline: 1.1315x; 1.1315x over previous
//
#include <hip/hip_runtime.h>
#include <math.h>

// Problem constants
#define BSZ    2
#define LSEQ   2048
#define DI     2048
#define DSTATE 8
#define DTRANK 256
#define KXP    (DTRANK + 2 * DSTATE)   // 272
#define NPAD   288                     // KXP padded to 18*16 for MFMA tiles
#define NC     64                      // scan chunks
#define CL     (LSEQ / NC)             // 32
#define KSPLIT 8                       // gemm1 K-splits (bf16 partials)
#define KCHUNK (DI / KSPLIT)           // 256

#define NWXP (288u * 2048u)            // 589824 (padded)
#define NWX  (272u * 2048u)            // 557056 (real)
#define NWDT (2048u * 256u)            // 524288

typedef __attribute__((ext_vector_type(8))) short bf16x8;
typedef __attribute__((ext_vector_type(4))) float f32x4;

static __device__ __forceinline__ unsigned short f2bf(float f) {
    unsigned u = __float_as_uint(f);
    u += 0x7fff + ((u >> 16) & 1);   // round-to-nearest-even
    return (unsigned short)(u >> 16);
}
static __device__ __forceinline__ float bf2f(unsigned short s) {
    return __uint_as_float((unsigned)s << 16);
}

static __device__ __forceinline__ float softplus_fast(float z) {
    const float e = __expf(-fabsf(z));
    return fmaxf(z, 0.0f) + __logf(1.0f + e);
}

// ---------------------------------------------------------------------------
// Convert weight matrices to bf16: W_xproj (272x2048 -> padded 288x2048) and
// W_dt (2048x256). 4 elems/thread. (x stays fp32; gemm1 converts in-register.)
// ---------------------------------------------------------------------------
__global__ __launch_bounds__(256) void convert_w(const float* __restrict__ Wx,
                                                 const float* __restrict__ Wdt,
                                                 unsigned short* __restrict__ Wxb,
                                                 unsigned short* __restrict__ Wdtb) {
    const unsigned tid = blockIdx.x * 256 + threadIdx.x;
    const unsigned i4 = tid * 4;
    float4 v;
    unsigned short* dst;
    unsigned j;
    if (i4 < NWXP) {
        j = i4;
        v = (j < NWX) ? *(const float4*)&Wx[j] : make_float4(0.f, 0.f, 0.f, 0.f);
        dst = Wxb;
    } else {
        j = i4 - NWXP;
        if (j >= NWDT) return;
        v = *(const float4*)&Wdt[j];
        dst = Wdtb;
    }
    ushort4 o;
    o.x = f2bf(v.x); o.y = f2bf(v.y); o.z = f2bf(v.z); o.w = f2bf(v.w);
    *(ushort4*)&dst[j] = o;
}

// ---------------------------------------------------------------------------
// GEMM1 (MFMA, split-K, LDS-staged, bf16 partials):
//   partb[ks][4096][288] = bf16( x[., ks-chunk] @ Wxb^T )
// BM=64, BN=288(full), BK=32. grid (64 Mtiles, 8 Ksplits) = 512 blocks.
// 4 waves = 2 rowhalves x 2 colhalves; wave = 32 rows x 144 cols (2x9 frags).
// A staged fp32->bf16 in-register; B staged coalesced. LDS stride 40 shorts.
// ---------------------------------------------------------------------------
#define G1RS 40
__global__ __launch_bounds__(256) void gemm1_mfma(const float* __restrict__ x,
                                                  const unsigned short* __restrict__ Wxb,
                                                  unsigned short* __restrict__ partb) {
    __shared__ __align__(16) unsigned short As[64 * G1RS];    //  5 KB
    __shared__ __align__(16) unsigned short Bs[288 * G1RS];   // 23 KB
    const int mt   = blockIdx.x;   // 0..63
    const int ks   = blockIdx.y;   // 0..7
    const int t    = threadIdx.x;
    const int wave = t >> 6;
    const int lane = t & 63;
    const int quad = lane >> 4;
    const int r    = lane & 15;
    const int rh   = wave >> 1;          // row half (32 rows)
    const int nh   = wave & 1;           // col half (144 cols)
    const int m0   = mt * 64;

    // staging maps
    const int arow = t >> 2;             // 0..63
    const int aoff = (t & 3) * 8;        // 0,8,16,24 (floats/shorts within BK)

    f32x4 acc[2][9];
#pragma unroll
    for (int f = 0; f < 2; f++)
#pragma unroll
        for (int n = 0; n < 9; n++) acc[f][n] = (f32x4)(0.0f);

    const int kbeg = ks * KCHUNK;
    for (int k0 = kbeg; k0 < kbeg + KCHUNK; k0 += 32) {
        // ---- load stage to regs (coalesced) ----
        const float4 a0 = *(const float4*)&x[(size_t)(m0 + arow) * DI + k0 + aoff];
        const float4 a1 = *(const float4*)&x[(size_t)(m0 + arow) * DI + k0 + aoff + 4];
        bf16x8 bstage[5];
#pragma unroll
        for (int j = 0; j < 5; j++) {
            const int i = t + j * 256;
            if (i < 1152)
                bstage[j] = *(const bf16x8*)&Wxb[(size_t)(i >> 2) * DI + k0 + (i & 3) * 8];
        }
        __syncthreads();   // prev iter's LDS reads done
        bf16x8 av;
        av[0] = (short)f2bf(a0.x); av[1] = (short)f2bf(a0.y);
        av[2] = (short)f2bf(a0.z); av[3] = (short)f2bf(a0.w);
        av[4] = (short)f2bf(a1.x); av[5] = (short)f2bf(a1.y);
        av[6] = (short)f2bf(a1.z); av[7] = (short)f2bf(a1.w);
        *(bf16x8*)&As[arow * G1RS + aoff] = av;
#pragma unroll
        for (int j = 0; j < 5; j++) {
            const int i = t + j * 256;
            if (i < 1152)
                *(bf16x8*)&Bs[(i >> 2) * G1RS + (i & 3) * 8] = bstage[j];
        }
        __syncthreads();   // writes visible

        // ---- fragments + MFMA ----
        bf16x8 af[2], bf[9];
#pragma unroll
        for (int f = 0; f < 2; f++)
            af[f] = *(const bf16x8*)&As[(rh * 32 + f * 16 + r) * G1RS + quad * 8];
#pragma unroll
        for (int nf = 0; nf < 9; nf++)
            bf[nf] = *(const bf16x8*)&Bs[(nh * 144 + nf * 16 + r) * G1RS + quad * 8];
#pragma unroll
        for (int f = 0; f < 2; f++)
#pragma unroll
            for (int nf = 0; nf < 9; nf++)
                acc[f][nf] = __builtin_amdgcn_mfma_f32_16x16x32_bf16(af[f], bf[nf], acc[f][nf], 0, 0, 0);
    }

    unsigned short* p = partb + (size_t)ks * 4096 * NPAD;
#pragma unroll
    for (int f = 0; f < 2; f++) {
        const int row0 = m0 + rh * 32 + f * 16 + quad * 4;
#pragma unroll
        for (int nf = 0; nf < 9; nf++) {
            const int col = nh * 144 + nf * 16 + r;
#pragma unroll
            for (int i = 0; i < 4; i++)
                p[(size_t)(row0 + i) * NPAD + col] = f2bf(acc[f][nf][i]);
        }
    }
}

// ---------------------------------------------------------------------------
// Reduce split-K bf16 partials -> xdbl fp32 [4096][272]; also emit dtr bf16
// [4096][256] for GEMM2. 4 cols/thread.
// ---------------------------------------------------------------------------
__global__ __launch_bounds__(256) void reduce1(const unsigned short* __restrict__ partb,
                                               float* __restrict__ xdbl,
                                               unsigned short* __restrict__ dtr) {
    const int tid = blockIdx.x * 256 + threadIdx.x;  // 4096*72
    const int row = tid / 72;
    const int c4  = (tid - row * 72) * 4;
    float4 s = make_float4(0.f, 0.f, 0.f, 0.f);
#pragma unroll
    for (int ks = 0; ks < KSPLIT; ks++) {
        const ushort4 v = *(const ushort4*)&partb[(size_t)ks * 4096 * NPAD + (size_t)row * NPAD + c4];
        s.x += bf2f(v.x); s.y += bf2f(v.y); s.z += bf2f(v.z); s.w += bf2f(v.w);
    }
    if (c4 < KXP) *(float4*)&xdbl[(size_t)row * KXP + c4] = s;
    if (c4 < DTRANK) {
        ushort4 o;
        o.x = f2bf(s.x); o.y = f2bf(s.y); o.z = f2bf(s.z); o.w = f2bf(s.w);
        *(ushort4*)&dtr[(size_t)row * DTRANK + c4] = o;
    }
}

// ---------------------------------------------------------------------------
// GEMM2 (MFMA, LDS-staged): delta[4096][2048] = softplus(dtr @ Wdtb^T + b_dt).
// K=256, BK=32. 128x128 block tile, 4 waves each 64x64 (4x4 frags).
// ---------------------------------------------------------------------------
#define G2RS 40
__global__ __launch_bounds__(256, 2) void gemm2_mfma(const unsigned short* __restrict__ dtr,
                                                     const unsigned short* __restrict__ Wdtb,
                                                     const float* __restrict__ bdt,
                                                     float* __restrict__ delta) {
    __shared__ __align__(16) unsigned short As[128 * G2RS];
    __shared__ __align__(16) unsigned short Bs[128 * G2RS];
    const int nt   = blockIdx.x;
    const int mt   = blockIdx.y;
    const int t    = threadIdx.x;
    const int wave = t >> 6;
    const int lane = t & 63;
    const int quad = lane >> 4;
    const int r    = lane & 15;
    const int m0 = mt * 128, n0 = nt * 128;
    const int mw = (wave >> 1) * 64, nw = (wave & 1) * 64;

    const int srow = t >> 1;             // 0..127
    const int sc   = (t & 1) * 16;       // 0 or 16 shorts

    f32x4 acc[4][4];
#pragma unroll
    for (int f = 0; f < 4; f++)
#pragma unroll
        for (int g = 0; g < 4; g++) acc[f][g] = (f32x4)(0.0f);

    for (int k0 = 0; k0 < DTRANK; k0 += 32) {
        const bf16x8 a0 = *(const bf16x8*)&dtr[(size_t)(m0 + srow) * DTRANK + k0 + sc];
        const bf16x8 a1 = *(const bf16x8*)&dtr[(size_t)(m0 + srow) * DTRANK + k0 + sc + 8];
        const bf16x8 b0 = *(const bf16x8*)&Wdtb[(size_t)(n0 + srow) * DTRANK + k0 + sc];
        const bf16x8 b1 = *(const bf16x8*)&Wdtb[(size_t)(n0 + srow) * DTRANK + k0 + sc + 8];
        __syncthreads();
        *(bf16x8*)&As[srow * G2RS + sc]     = a0;
        *(bf16x8*)&As[srow * G2RS + sc + 8] = a1;
        *(bf16x8*)&Bs[srow * G2RS + sc]     = b0;
        *(bf16x8*)&Bs[srow * G2RS + sc + 8] = b1;
        __syncthreads();

        bf16x8 a[4], b[4];
#pragma unroll
        for (int f = 0; f < 4; f++)
            a[f] = *(const bf16x8*)&As[(mw + f * 16 + r) * G2RS + quad * 8];
#pragma unroll
        for (int g = 0; g < 4; g++)
            b[g] = *(const bf16x8*)&Bs[(nw + g * 16 + r) * G2RS + quad * 8];
#pragma unroll
        for (int f = 0; f < 4; f++)
#pragma unroll
            for (int g = 0; g < 4; g++)
                acc[f][g] = __builtin_amdgcn_mfma_f32_16x16x32_bf16(a[f], b[g], acc[f][g], 0, 0, 0);
    }

#pragma unroll
    for (int f = 0; f < 4; f++) {
        const int row0 = m0 + mw + f * 16 + quad * 4;
#pragma unroll
        for (int g = 0; g < 4; g++) {
            const int col = n0 + nw + g * 16 + r;
            const float bv = bdt[col];
#pragma unroll
            for (int i = 0; i < 4; i++)
                delta[(size_t)(row0 + i) * DI + col] = softplus_fast(acc[f][g][i] + bv);
        }
    }
}

// ---------------------------------------------------------------------------
// Scan pass 1: per (b, chunk, d) chunk summary (P = prod dA, H = h_end), h=0.
// grid: BSZ*NC*8 = 1024 blocks. B rows staged in LDS (broadcast reads).
// ---------------------------------------------------------------------------
__global__ __launch_bounds__(256) void scan_pass1(const float* __restrict__ x,
                                                  const float* __restrict__ delta,
                                                  const float* __restrict__ xdbl,
                                                  const float* __restrict__ Alog,
                                                  float* __restrict__ Pb,
                                                  float* __restrict__ Hb) {
    __shared__ __align__(16) float Ls[CL * 8];
    const int bi   = blockIdx.x;
    const int b    = bi >> 9;
    const int c    = (bi >> 3) & 63;
    const int dblk = bi & 7;
    const int d    = dblk * 256 + threadIdx.x;
    const int l0   = c * CL;
    const size_t row0 = (size_t)b * LSEQ + l0;

    if (threadIdx.x < CL * 2) {
        const int l = threadIdx.x >> 1, part = (threadIdx.x & 1) * 4;
        const float4 v = *(const float4*)&xdbl[(row0 + l) * KXP + DTRANK + part];
        *(float4*)&Ls[l * 8 + part] = v;
    }

    float A[8], h[8], P[8];
#pragma unroll
    for (int n = 0; n < 8; n++) {
        A[n] = -__expf(Alog[d * 8 + n]);
        h[n] = 0.f;
        P[n] = 1.f;
    }
    __syncthreads();

#pragma unroll 4
    for (int l = 0; l < CL; l++) {
        const size_t row = row0 + l;
        const float dl = delta[row * DI + d];
        const float xv = x[row * DI + d];
        const float du = dl * xv;
#pragma unroll
        for (int n = 0; n < 8; n++) {
            const float dA = __expf(dl * A[n]);
            h[n] = dA * h[n] + du * Ls[l * 8 + n];
            P[n] *= dA;
        }
    }
    const size_t base = ((size_t)(b * NC + c) * DI + d) * 8;
    *(float4*)&Pb[base]     = make_float4(P[0], P[1], P[2], P[3]);
    *(float4*)&Pb[base + 4] = make_float4(P[4], P[5], P[6], P[7]);
    *(float4*)&Hb[base]     = make_float4(h[0], h[1], h[2], h[3]);
    *(float4*)&Hb[base + 4] = make_float4(h[4], h[5], h[6], h[7]);
}

// ---------------------------------------------------------------------------
// Scan pass 2: combine NC chunk summaries -> h0 entering each chunk.
// One thread per (b, d, n) scalar chain: 32768 threads, coalesced.
// ---------------------------------------------------------------------------
__global__ __launch_bounds__(256) void scan_pass2(const float* __restrict__ Pb,
                                                  const float* __restrict__ Hb,
                                                  float* __restrict__ h0) {
    const int t   = blockIdx.x * 256 + threadIdx.x;  // 0..32767
    const int b   = t >> 14;
    const int rem = t & 16383;                       // d*8+n
    float h = 0.f;
#pragma unroll 4
    for (int c = 0; c < NC; c++) {
        const size_t base = (size_t)(b * NC + c) * (DI * 8) + rem;
        h0[base] = h;
        h = Pb[base] * h + Hb[base];
    }
}

// ---------------------------------------------------------------------------
// Scan pass 3: re-scan each chunk from h0, produce y. B/C staged in LDS.
// ---------------------------------------------------------------------------
__global__ __launch_bounds__(256) void scan_pass3(const float* __restrict__ x,
                                                  const float* __restrict__ delta,
                                                  const float* __restrict__ xdbl,
                                                  const float* __restrict__ Alog,
                                                  const float* __restrict__ Dp,
                                                  const float* __restrict__ h0,
                                                  float* __restrict__ y) {
    __shared__ __align__(16) float Ls[CL * 16];
    const int bi   = blockIdx.x;
    const int b    = bi >> 9;
    const int c    = (bi >> 3) & 63;
    const int dblk = bi & 7;
    const int d    = dblk * 256 + threadIdx.x;
    const int l0   = c * CL;
    const size_t row0 = (size_t)b * LSEQ + l0;

    if (threadIdx.x < CL * 4) {
        const int l = threadIdx.x >> 2, part = (threadIdx.x & 3) * 4;
        const float4 v = *(const float4*)&xdbl[(row0 + l) * KXP + DTRANK + part];
        *(float4*)&Ls[l * 16 + part] = v;
    }

    float A[8], h[8];
    const size_t hbase = ((size_t)(b * NC + c) * DI + d) * 8;
    const float4 h0a = *(const float4*)&h0[hbase];
    const float4 h0b = *(const float4*)&h0[hbase + 4];
    h[0] = h0a.x; h[1] = h0a.y; h[2] = h0a.z; h[3] = h0a.w;
    h[4] = h0b.x; h[5] = h0b.y; h[6] = h0b.z; h[7] = h0b.w;
#pragma unroll
    for (int n = 0; n < 8; n++) A[n] = -__expf(Alog[d * 8 + n]);
    const float Dpar = Dp[d];
    __syncthreads();

#pragma unroll 4
    for (int l = 0; l < CL; l++) {
        const size_t row = row0 + l;
        const float dl = delta[row * DI + d];
        const float xv = x[row * DI + d];
        const float du = dl * xv;
        float yv = 0.f;
#pragma unroll
        for (int n = 0; n < 8; n++) {
            const float dA = __expf(dl * A[n]);
            h[n] = dA * h[n] + du * Ls[l * 16 + n];
            yv += h[n] * Ls[l * 16 + 8 + n];
        }
        yv += xv * Dpar;
        y[row * DI + d] = yv;
    }
}

// ---------------------------------------------------------------------------
extern "C" void kernel_launch(void* const* d_in, const int* in_sizes, int n_in,
                              void* d_out, int out_size, void* d_ws, size_t ws_size,
                              hipStream_t stream) {
    const float* x    = (const float*)d_in[0];
    const float* Wx   = (const float*)d_in[1];
    const float* Wdt  = (const float*)d_in[2];
    const float* bdt  = (const float*)d_in[3];
    const float* Alog = (const float*)d_in[4];
    const float* Dp   = (const float*)d_in[5];
    float* y = (float*)d_out;

    // Workspace (floats unless noted). delta aliases partb (dead after reduce1).
    float* ws    = (float*)d_ws;
    unsigned short* partb = (unsigned short*)ws;     // 8*4096*288 bf16
    float* delta = ws;                               // alias (after reduce1)
    float* xdbl  = ws + 8388608;
    float* Pb    = xdbl + 1114112;
    float* Hb    = Pb + 2097152;
    float* h0    = Hb + 2097152;
    unsigned short* Wxb  = (unsigned short*)(h0 + 2097152);
    unsigned short* Wdtb = Wxb + (size_t)NWXP;
    unsigned short* dtr  = Wdtb + (size_t)NWDT;

    dim3 blk(256);
    hipLaunchKernelGGL(convert_w, dim3((NWXP + NWDT) / 4 / 256), blk, 0, stream,
                       Wx, Wdt, Wxb, Wdtb);
    hipLaunchKernelGGL(gemm1_mfma, dim3(64, KSPLIT), blk, 0, stream, x, Wxb, partb);
    hipLaunchKernelGGL(reduce1, dim3(4096 * 72 / 256), blk, 0, stream, partb, xdbl, dtr);
    hipLaunchKernelGGL(gemm2_mfma, dim3(16, 32), blk, 0, stream, dtr, Wdtb, bdt, delta);
    hipLaunchKernelGGL(scan_pass1, dim3(BSZ * NC * 8), blk, 0, stream, x, delta, xdbl, Alog, Pb, Hb);
    hipLaunchKernelGGL(scan_pass2, dim3(128), blk, 0, stream, Pb, Hb, h0);
    hipLaunchKernelGGL(scan_pass3, dim3(BSZ * NC * 8), blk, 0, stream, x, delta, xdbl, Alog, Dp, h0, y);
}